// Round 3
// baseline (92.345 us; speedup 1.0000x reference)
//
#include <hip/hip_runtime.h>
#include <math.h>

#define DD 64

// tanh(a) = (e-1)/(e+1), e = exp2(a * 2*log2(e)); v_exp_f32 + v_rcp_f32.
__device__ __forceinline__ float fast_tanh(float a) {
    a = fminf(fmaxf(a, -15.0f), 15.0f);
    const float e = __builtin_amdgcn_exp2f(a * 2.885390081777927f);
    return (e - 1.0f) * __builtin_amdgcn_rcpf(e + 1.0f);
}

__device__ __forceinline__ float wave_sum(float v) {
#pragma unroll
    for (int off = 32; off; off >>= 1) v += __shfl_xor(v, off);
    return v;
}
__device__ __forceinline__ float wave_max(float v) {
#pragma unroll
    for (int off = 32; off; off >>= 1) v = fmaxf(v, __shfl_xor(v, off));
    return v;
}

// zl = xi + dot(w, zsh), 4 independent FMA chains.
__device__ __forceinline__ float matvec_row(const float* __restrict__ w,
                                            const float* zsh, float xi) {
    float a0 = xi, a1 = 0.f, a2 = 0.f, a3 = 0.f;
#pragma unroll
    for (int j = 0; j < DD; j += 16) {
        const float4 z0 = *reinterpret_cast<const float4*>(&zsh[j]);
        const float4 z1 = *reinterpret_cast<const float4*>(&zsh[j + 4]);
        const float4 z2 = *reinterpret_cast<const float4*>(&zsh[j + 8]);
        const float4 z3 = *reinterpret_cast<const float4*>(&zsh[j + 12]);
        a0 = fmaf(w[j],      z0.x, a0); a0 = fmaf(w[j + 1],  z0.y, a0);
        a0 = fmaf(w[j + 2],  z0.z, a0); a0 = fmaf(w[j + 3],  z0.w, a0);
        a1 = fmaf(w[j + 4],  z1.x, a1); a1 = fmaf(w[j + 5],  z1.y, a1);
        a1 = fmaf(w[j + 6],  z1.z, a1); a1 = fmaf(w[j + 7],  z1.w, a1);
        a2 = fmaf(w[j + 8],  z2.x, a2); a2 = fmaf(w[j + 9],  z2.y, a2);
        a2 = fmaf(w[j + 10], z2.z, a2); a2 = fmaf(w[j + 11], z2.w, a2);
        a3 = fmaf(w[j + 12], z3.x, a3); a3 = fmaf(w[j + 13], z3.y, a3);
        a3 = fmaf(w[j + 14], z3.z, a3); a3 = fmaf(w[j + 15], z3.w, a3);
    }
    return (a0 + a1) + (a2 + a3);
}

// One Picard apply G(z) = tanh(W z + x), z broadcast via 256B LDS.
// Single-wave block: lockstep, wave_barrier = compiler ordering fence only.
__device__ __forceinline__ float apply_G(const float* __restrict__ w, float* zsh,
                                         float xi, float z, int lane) {
    zsh[lane] = z;
    __builtin_amdgcn_wave_barrier();
    const float zl = matvec_row(w, zsh, xi);
    __builtin_amdgcn_wave_barrier();
    return fast_tanh(zl);
}

// One wave per batch row; lane i owns element i and W row i in registers.
// Anderson(1)-accelerated fixed point with guaranteed-convergent Picard polish.
__global__ __launch_bounds__(64)
void tanh_fixed_point(const float* __restrict__ x,
                      const float* __restrict__ W,
                      float* __restrict__ out)
{
    __shared__ float zsh[DD];
    const int lane = threadIdx.x;
    const int b    = blockIdx.x;

    float w[DD];
#pragma unroll
    for (int j = 0; j < DD; j += 4) {
        const float4 v = *reinterpret_cast<const float4*>(W + lane * DD + j);
        w[j] = v.x; w[j + 1] = v.y; w[j + 2] = v.z; w[j + 3] = v.w;
    }

    const float xi = x[b * DD + lane];
    float z  = fast_tanh(xi);                 // z0 = tanh(x), as reference
    float f1 = apply_G(w, zsh, xi, z, lane);  // first Picard apply
    float r1 = f1 - z;
    float zc = f1;
    bool done = wave_max(fabsf(r1)) < 1e-6f;  // wave-uniform

    // Anderson(1): scalar mixing theta from two wave-reduced dot products.
    for (int k = 0; k < 12 && !done; ++k) {
        const float f2 = apply_G(w, zsh, xi, zc, lane);
        const float r2 = f2 - zc;
        const float d  = r2 - r1;
        const float num = wave_sum(r2 * d);
        const float den = wave_sum(d * d);
        float theta = (den > 1e-30f) ? num * __builtin_amdgcn_rcpf(den) : 0.0f;
        theta = fminf(fmaxf(theta, -4.0f), 4.0f);   // bounded extrapolation
        done = wave_max(fabsf(r2)) < 1e-6f;
        zc = done ? f2 : fmaf(-theta, f2 - f1, f2);
        f1 = f2; r1 = r2;
    }

    // Plain Picard polish (contraction, rho ~< 0.6: always converges).
    for (int k = 0; k < 64 && !done; ++k) {
        const float zn = apply_G(w, zsh, xi, zc, lane);
        done = wave_max(fabsf(zn - zc)) < 1e-6f;
        zc = zn;
    }
    z = zc;

    // Mirror reference: zero rows with ||z - tanh(zW^T+x)||_2 > 1e-4.
    const float g = z - apply_G(w, zsh, xi, z, lane);
    const float s = wave_sum(g * g);
    if (s > 1e-8f) z = 0.0f;

    out[b * DD + lane] = z;
}

extern "C" void kernel_launch(void* const* d_in, const int* in_sizes, int n_in,
                              void* d_out, int out_size, void* d_ws, size_t ws_size,
                              hipStream_t stream)
{
    const float* x = (const float*)d_in[0];   // [B, 64] fp32
    const float* W = (const float*)d_in[1];   // [64, 64] fp32
    float* out     = (float*)d_out;           // [B, 64] fp32
    const int B = in_sizes[0] / DD;           // 4096
    tanh_fixed_point<<<B, DD, 0, stream>>>(x, W, out);
}

// Round 4
// 74.836 us; speedup vs baseline: 1.2340x; 1.2340x over previous
//
#include <hip/hip_runtime.h>
#include <math.h>

#define DD  64
#define WPB 4    // rows (waves) per 256-thread block

// tanh(a) = (e-1)/(e+1), e = exp2(a*2*log2(e)); v_exp_f32 + v_rcp_f32.
// No clamp: |zl| <= |x|max(~4.6) + sum|W row|(<=8) ~ 13 << 44 (f32 exp2 overflow),
// so e is finite and (e-1)*rcp(e+1) -> 1.0 cleanly at the extremes.
__device__ __forceinline__ float fast_tanh(float a) {
    const float e = __builtin_amdgcn_exp2f(a * 2.885390081777927f);
    return (e - 1.0f) * __builtin_amdgcn_rcpf(e + 1.0f);
}

// zl = xi + dot(w, zs); 4 independent FMA chains (chain 64 -> 16 deps).
__device__ __forceinline__ float matvec_row(const float* __restrict__ w,
                                            const float* zs, float xi) {
    float a0 = xi, a1 = 0.f, a2 = 0.f, a3 = 0.f;
#pragma unroll
    for (int j = 0; j < DD; j += 16) {
        const float4 z0 = *reinterpret_cast<const float4*>(&zs[j]);
        const float4 z1 = *reinterpret_cast<const float4*>(&zs[j + 4]);
        const float4 z2 = *reinterpret_cast<const float4*>(&zs[j + 8]);
        const float4 z3 = *reinterpret_cast<const float4*>(&zs[j + 12]);
        a0 = fmaf(w[j],      z0.x, a0); a0 = fmaf(w[j + 1],  z0.y, a0);
        a0 = fmaf(w[j + 2],  z0.z, a0); a0 = fmaf(w[j + 3],  z0.w, a0);
        a1 = fmaf(w[j + 4],  z1.x, a1); a1 = fmaf(w[j + 5],  z1.y, a1);
        a1 = fmaf(w[j + 6],  z1.z, a1); a1 = fmaf(w[j + 7],  z1.w, a1);
        a2 = fmaf(w[j + 8],  z2.x, a2); a2 = fmaf(w[j + 9],  z2.y, a2);
        a2 = fmaf(w[j + 10], z2.z, a2); a2 = fmaf(w[j + 11], z2.w, a2);
        a3 = fmaf(w[j + 12], z3.x, a3); a3 = fmaf(w[j + 13], z3.y, a3);
        a3 = fmaf(w[j + 14], z3.z, a3); a3 = fmaf(w[j + 15], z3.w, a3);
    }
    return (a0 + a1) + (a2 + a3);
}

// One Picard apply G(z) = tanh(W z + x). z broadcast through this wave's
// private 256B LDS slice. Single-wave lockstep: wave_barrier is only a
// compiler ordering fence (no s_barrier — waves in the block stay decoupled).
__device__ __forceinline__ float apply_G(const float* __restrict__ w, float* zs,
                                         float xi, float z, int lane) {
    zs[lane] = z;
    __builtin_amdgcn_wave_barrier();
    const float zl = matvec_row(w, zs, xi);
    __builtin_amdgcn_wave_barrier();
    return fast_tanh(zl);
}

// One wave per batch row; lane i owns element i and W row i in registers.
// 4 independent rows per block (guards against per-CU workgroup-slot caps
// on tiny 64-thread blocks). Convergence check via __all(): v_cmp->vcc +
// s_cmp vcc,exec — ~free, so we check every iteration (earliest exit).
__global__ __launch_bounds__(256)
void tanh_fixed_point(const float* __restrict__ x,
                      const float* __restrict__ W,
                      float* __restrict__ out)
{
    __shared__ float zsh[WPB][DD];
    const int lane = threadIdx.x & 63;
    const int wid  = threadIdx.x >> 6;
    const int b    = blockIdx.x * WPB + wid;
    float* zs = zsh[wid];

    float w[DD];
#pragma unroll
    for (int j = 0; j < DD; j += 4) {
        const float4 v = *reinterpret_cast<const float4*>(W + lane * DD + j);
        w[j] = v.x; w[j + 1] = v.y; w[j + 2] = v.z; w[j + 3] = v.w;
    }

    const float xi = x[b * DD + lane];
    float z = fast_tanh(xi);            // z0 = tanh(x), as reference

    for (int it = 0; it < 200; ++it) {
        const float zn = apply_G(w, zs, xi, z, lane);
        const bool conv = fabsf(zn - z) < 1e-6f;
        z = zn;
        if (__all(conv)) break;         // wave-uniform, ~3 instrs
    }

    // Mirror reference: zero rows with ||z - tanh(zW^T+x)||_2 > 1e-4.
    // (Reference's global-Frobenius stop => it zeroes nothing when Newton
    // converges; ours only fires if a row truly stalls. Once per wave.)
    const float g = z - apply_G(w, zs, xi, z, lane);
    float s = g * g;
#pragma unroll
    for (int off = 32; off; off >>= 1)
        s += __shfl_xor(s, off);
    if (s > 1e-8f) z = 0.0f;

    out[b * DD + lane] = z;
}

extern "C" void kernel_launch(void* const* d_in, const int* in_sizes, int n_in,
                              void* d_out, int out_size, void* d_ws, size_t ws_size,
                              hipStream_t stream)
{
    const float* x = (const float*)d_in[0];   // [B, 64] fp32
    const float* W = (const float*)d_in[1];   // [64, 64] fp32
    float* out     = (float*)d_out;           // [B, 64] fp32
    const int B = in_sizes[0] / DD;           // 4096
    tanh_fixed_point<<<B / WPB, 64 * WPB, 0, stream>>>(x, W, out);
}

// Round 5
// 74.466 us; speedup vs baseline: 1.2401x; 1.0050x over previous
//
#include <hip/hip_runtime.h>
#include <math.h>

#define DD  64
#define WPB 4    // rows (waves) per 256-thread block

// tanh(a) = (e-1)/(e+1), e = exp2(a*2*log2(e)); v_exp_f32 + v_rcp_f32.
// No clamp: |zl| <= |x|max(~4.6) + sum|W row|(<=8) ~ 13 << 44 (f32 exp2
// overflow), so e stays finite and (e-1)*rcp(e+1) -> 1.0 at the extremes.
__device__ __forceinline__ float fast_tanh(float a) {
    const float e = __builtin_amdgcn_exp2f(a * 2.885390081777927f);
    return (e - 1.0f) * __builtin_amdgcn_rcpf(e + 1.0f);
}

// zl = xi + dot(w, zs); 4 independent FMA chains (chain 64 -> 16 deps).
__device__ __forceinline__ float matvec_row(const float* __restrict__ w,
                                            const float* zs, float xi) {
    float a0 = xi, a1 = 0.f, a2 = 0.f, a3 = 0.f;
#pragma unroll
    for (int j = 0; j < DD; j += 16) {
        const float4 z0 = *reinterpret_cast<const float4*>(&zs[j]);
        const float4 z1 = *reinterpret_cast<const float4*>(&zs[j + 4]);
        const float4 z2 = *reinterpret_cast<const float4*>(&zs[j + 8]);
        const float4 z3 = *reinterpret_cast<const float4*>(&zs[j + 12]);
        a0 = fmaf(w[j],      z0.x, a0); a0 = fmaf(w[j + 1],  z0.y, a0);
        a0 = fmaf(w[j + 2],  z0.z, a0); a0 = fmaf(w[j + 3],  z0.w, a0);
        a1 = fmaf(w[j + 4],  z1.x, a1); a1 = fmaf(w[j + 5],  z1.y, a1);
        a1 = fmaf(w[j + 6],  z1.z, a1); a1 = fmaf(w[j + 7],  z1.w, a1);
        a2 = fmaf(w[j + 8],  z2.x, a2); a2 = fmaf(w[j + 9],  z2.y, a2);
        a2 = fmaf(w[j + 10], z2.z, a2); a2 = fmaf(w[j + 11], z2.w, a2);
        a3 = fmaf(w[j + 12], z3.x, a3); a3 = fmaf(w[j + 13], z3.y, a3);
        a3 = fmaf(w[j + 14], z3.z, a3); a3 = fmaf(w[j + 15], z3.w, a3);
    }
    return (a0 + a1) + (a2 + a3);
}

// One Picard apply G(z) = tanh(W z + x). z broadcast through this wave's
// private 256B LDS slice. Single-wave lockstep: wave_barrier is only a
// compiler ordering fence (no s_barrier — waves stay decoupled).
__device__ __forceinline__ float apply_G(const float* __restrict__ w, float* zs,
                                         float xi, float z, int lane) {
    zs[lane] = z;
    __builtin_amdgcn_wave_barrier();
    const float zl = matvec_row(w, zs, xi);
    __builtin_amdgcn_wave_barrier();
    return fast_tanh(zl);
}

// One wave per batch row; lane i owns element i and W row i in registers.
// EXIT TOL 2.5e-6: safely above the exp2/rcp evaluation-noise floor (~5e-7
// after 1/(1-rho) amplification) — the old 1e-6 sat AT the floor, so unlucky
// rows never exited and ran to the 200-iter cap (kernel time = cap x ~320cyc
// = the observed ~26us, invariant across r1/r2/r4 micro-opts).
// Error at exit <= tol*rho/(1-rho) ~ 4e-6/elem; residual 2-norm <= 5e-5,
// safely below the 1e-4 zeroing threshold. Cap 64: rho<=0.6 -> 0.6^64~6e-15,
// unreachable for any contracting row.
__global__ __launch_bounds__(256)
void tanh_fixed_point(const float* __restrict__ x,
                      const float* __restrict__ W,
                      float* __restrict__ out)
{
    __shared__ float zsh[WPB][DD];
    const int lane = threadIdx.x & 63;
    const int wid  = threadIdx.x >> 6;
    const int b    = blockIdx.x * WPB + wid;
    float* zs = zsh[wid];

    float w[DD];
#pragma unroll
    for (int j = 0; j < DD; j += 4) {
        const float4 v = *reinterpret_cast<const float4*>(W + lane * DD + j);
        w[j] = v.x; w[j + 1] = v.y; w[j + 2] = v.z; w[j + 3] = v.w;
    }

    const float xi = x[b * DD + lane];
    float z = fast_tanh(xi);            // z0 = tanh(x), as reference

    for (int it = 0; it < 64; ++it) {
        const float zn = apply_G(w, zs, xi, z, lane);
        const bool conv = fabsf(zn - z) < 2.5e-6f;
        z = zn;
        if (__all(conv)) break;         // wave-uniform, ~3 instrs
    }

    // Mirror reference: zero rows with ||z - tanh(zW^T+x)||_2 > 1e-4.
    const float g = z - apply_G(w, zs, xi, z, lane);
    float s = g * g;
#pragma unroll
    for (int off = 32; off; off >>= 1)
        s += __shfl_xor(s, off);
    if (s > 1e-8f) z = 0.0f;

    out[b * DD + lane] = z;
}

extern "C" void kernel_launch(void* const* d_in, const int* in_sizes, int n_in,
                              void* d_out, int out_size, void* d_ws, size_t ws_size,
                              hipStream_t stream)
{
    const float* x = (const float*)d_in[0];   // [B, 64] fp32
    const float* W = (const float*)d_in[1];   // [64, 64] fp32
    float* out     = (float*)d_out;           // [B, 64] fp32
    const int B = in_sizes[0] / DD;           // 4096
    tanh_fixed_point<<<B / WPB, 64 * WPB, 0, stream>>>(x, W, out);
}